// Round 10
// baseline (121.684 us; speedup 1.0000x reference)
//
#include <hip/hip_runtime.h>
#include <hip/hip_bf16.h>

#define BH 120
#define BW 240
#define NLVL 5
#define NCAM 6
#define CH 128
#define FH 64
#define FW 176
#define CIN 655
#define CINP 672            // padded to 21*32
#define NCT 21
#define FROWS 124           // padded rows; 0..121 used, 122..123 slack (read-only pad)
#define FCOLS 242
#define NPIX (BH*BW)

typedef __hip_bfloat16 bf16;
typedef __attribute__((ext_vector_type(8))) short s16x8;
typedef __attribute__((ext_vector_type(4))) float f32x4;
typedef unsigned int uint;
typedef __attribute__((ext_vector_type(4), aligned(4))) uint uint4a;

#define G_AS __attribute__((address_space(1)))
#define L_AS __attribute__((address_space(3)))

__device__ __forceinline__ float bf2f(unsigned short u) {
    union { unsigned int i; float f; } c; c.i = ((unsigned int)u) << 16; return c.f;
}
__device__ __forceinline__ uint f2bu(float x) {
    return (uint)__hip_bfloat16_raw(__float2bfloat16(x)).x;
}
__device__ __forceinline__ float blo(uint u) {
    union { uint i; float f; } c; c.i = u << 16; return c.f;
}
__device__ __forceinline__ float bhi(uint u) {
    union { uint i; float f; } c; c.i = u & 0xFFFF0000u; return c.f;
}

// ---------------------------------------------------------------------------
// Kernel T: transpose cam_feat [6][128][64][176] f32 -> camt bf16 [6][64][176][128]
// ---------------------------------------------------------------------------
__global__ __launch_bounds__(256) void transpose_kernel(
    const float* __restrict__ in, bf16* __restrict__ out)
{
    __shared__ float t[32][129];
    int n = blockIdx.z, h = blockIdx.y, w0 = blockIdx.x * 32;
    int wlim = min(32, FW - w0);
    int wx = threadIdx.x & 31, cg = threadIdx.x >> 5;
    if (wx < wlim) {
        #pragma unroll
        for (int k = 0; k < 16; ++k) {
            int c = cg + k * 8;
            t[wx][c] = in[((n*CH + c)*FH + h)*FW + w0 + wx];
        }
    }
    __syncthreads();
    int c2 = threadIdx.x & 127, wi = threadIdx.x >> 7;
    for (int w = wi; w < wlim; w += 2)
        out[((n*FH + h)*FW + w0 + w)*CH + c2] = __float2bfloat16(t[w][c2]);
}

// ---------------------------------------------------------------------------
// Kernel W2: conv_w [128][655][3][3] f32 -> wbf2 packed A-fragments:
// chunk C = (off*21 + ct)*8 + mg  (mg = oc>>4), 64 lanes x 8 bf16 each;
// lane l holds oc = mg*16 + (l&15), cin = ct*32 + (l>>4)*8 + e.
// Exactly the mfma_f32_16x16x32_bf16 A-operand layout -> loadA is 4
// fully-coalesced 1KB reads. Tail cin >= 655 zeroed.
// Block = one (ct, mg): stage 16 oc-rows x 288 floats (contiguous) in LDS.
// ---------------------------------------------------------------------------
__global__ __launch_bounds__(256) void wprep2_kernel(
    const float* __restrict__ w, bf16* __restrict__ wbf2)
{
    __shared__ float lw[4608];
    int bid = blockIdx.x;              // 0..167
    int ct = bid >> 3, mg = bid & 7;
    int tid = threadIdx.x;
    for (int idx = tid; idx < 4608; idx += 256) {
        int r = idx / 288, i = idx - r*288;
        int cl = i / 9, k = i - cl*9;
        int cin = ct*32 + cl;
        int oc = mg*16 + r;
        lw[idx] = (cin < CIN) ? w[((size_t)oc*CIN + cin)*9 + k] : 0.f;
    }
    __syncthreads();
    for (int it = tid; it < 576; it += 256) {
        int off = it >> 6, lane = it & 63;
        int r = lane & 15, kg = lane >> 4;
        s16x8 o;
        #pragma unroll
        for (int e = 0; e < 8; ++e)
            o[e] = (short)f2bu(lw[r*288 + (kg*8 + e)*9 + off]);
        *(s16x8*)(wbf2 + ((size_t)((off*NCT + ct)*8 + mg)*64 + lane)*8) = o;
    }
}

// ---------------------------------------------------------------------------
// Kernel Z: zero the 724 border pixels across all 672 cin.
// ---------------------------------------------------------------------------
__global__ __launch_bounds__(128) void border_kernel(bf16* __restrict__ feat)
{
    int b = blockIdx.x;            // 0..723
    int row, col;
    if (b < 242)      { row = 0;   col = b; }
    else if (b < 484) { row = 121; col = b - 242; }
    else if (b < 604) { row = b - 484 + 1; col = 0; }
    else              { row = b - 604 + 1; col = 241; }
    s16x8* p = (s16x8*)(feat + ((size_t)row*FCOLS + col)*CINP);
    int t = threadIdx.x;
    if (t < 84) p[t] = (s16x8){0,0,0,0,0,0,0,0};
}

// ---------------------------------------------------------------------------
// Kernel P v3: 1 wave = 1 BEV pixel; camt bf16; XCD-swizzled blockIdx.
// (unchanged from round 7-9 passing versions)
// ---------------------------------------------------------------------------
__global__ __launch_bounds__(256) void proj_kernel(
    const bf16* __restrict__ camt,
    const float* __restrict__ e2c,
    const int* __restrict__ pimgh, const int* __restrict__ pimgw,
    bf16* __restrict__ feat)
{
    __shared__ int   s_soff[4][32];
    __shared__ float s_w4[4][30][4];
    __shared__ int   s_val[4][32];

    const int wv = threadIdx.x >> 6;
    const int lane = threadIdx.x & 63;
    const int bid = blockIdx.x;                      // 7200 blocks
    const int swz = (bid & 7) * 900 + (bid >> 3);    // T1 XCD swizzle
    const int pix = swz * 4 + wv;
    const int bx = pix % BW, by = pix / BW;
    float xw = (float)(-30.0 + bx * (60.0/239.0)); if (bx == BW-1) xw = 30.f;
    float yw = (float)(-15.0 + by * (30.0/119.0)); if (by == BH-1) yw = 15.f;

    const bool act = lane < 30;
    int valid = 0, ix = 0, iy = 0, cam = 0;
    float fx = 0.f, fy = 0.f;
    if (act) {
        int l = lane / 6; cam = lane - l*6;
        float h = -1.f + 0.5f * (float)l;
        const float* M = e2c + cam * 16;
        float cx = M[0]*xw + M[1]*yw + M[2]*h  + M[3];
        float cy = M[4]*xw + M[5]*yw + M[6]*h  + M[7];
        float cz = M[8]*xw + M[9]*yw + M[10]*h + M[11];
        float iw = (float)pimgw[0], ih = (float)pimgh[0];
        float px = ((cx/cz + 1e-9f)/iw - 0.5f) * 2.f;
        float py = ((cy/cz + 1e-9f)/ih - 0.5f) * 2.f;
        valid = (cz > 1e-9f) && (px > -1.f) && (px < 1.f)
                             && (py > -1.f) && (py < 1.f);
        float xs = ((px + 1.f)*(float)FW - 1.f) * 0.5f;
        float ys = ((py + 1.f)*(float)FH - 1.f) * 0.5f;
        float x0 = floorf(xs), y0 = floorf(ys);
        fx = xs - x0; fy = ys - y0;
        ix = (int)x0; iy = (int)y0;
        s_val[wv][lane] = valid;
    }
    __syncthreads();
    if (act) {
        int lbase = (lane / 6) * 6;
        int cnt = s_val[wv][lbase] + s_val[wv][lbase+1] + s_val[wv][lbase+2]
                + s_val[wv][lbase+3] + s_val[wv][lbase+4] + s_val[wv][lbase+5];
        float inv = (cnt > 0) ? (1.f / (float)cnt) : 0.f;
        float sc = valid ? inv : 0.f;
        int bx0 = min(max(ix, 0), FW-2);
        int by0 = min(max(iy, 0), FH-2);
        float gx0 = (1.f - fx) * sc, gx1 = fx * sc;
        float wx0 = 0.f, wx1 = 0.f;
        if (ix >= 0)     { if (ix == bx0) wx0 += gx0; else wx1 += gx0; }
        if (ix+1 <= FW-1){ if (ix+1 == bx0) wx0 += gx1; else wx1 += gx1; }
        float wy0 = 0.f, wy1 = 0.f;
        float gy0 = 1.f - fy, gy1 = fy;
        if (iy >= 0)     { if (iy == by0) wy0 += gy0; else wy1 += gy0; }
        if (iy+1 <= FH-1){ if (iy+1 == by0) wy0 += gy1; else wy1 += gy1; }
        s_w4[wv][lane][0] = wx0 * wy0;
        s_w4[wv][lane][1] = wx0 * wy1;
        s_w4[wv][lane][2] = wx1 * wy0;
        s_w4[wv][lane][3] = wx1 * wy1;
        s_soff[wv][lane] = valid ? ((cam*FH + by0)*FW + bx0)*CH : -1;
    }
    __syncthreads();

    const int c2 = lane * 2;
    float va[NLVL], vb[NLVL];
    #pragma unroll
    for (int l = 0; l < NLVL; ++l) { va[l] = 0.f; vb[l] = 0.f; }

    #pragma unroll
    for (int l = 0; l < NLVL; ++l) {
        #pragma unroll
        for (int cm = 0; cm < NCAM; ++cm) {
            int id = l*6 + cm;
            int so = s_soff[wv][id];
            if (so >= 0) {                       // wave-uniform branch
                const bf16* bp = camt + so + c2;
                uint q0 = *(const uint*)(bp);
                uint q2 = *(const uint*)(bp + CH);
                uint q1 = *(const uint*)(bp + FW*CH);
                uint q3 = *(const uint*)(bp + FW*CH + CH);
                float w0 = s_w4[wv][id][0], w1 = s_w4[wv][id][1];
                float w2 = s_w4[wv][id][2], w3 = s_w4[wv][id][3];
                va[l] += w0*blo(q0) + w1*blo(q1) + w2*blo(q2) + w3*blo(q3);
                vb[l] += w0*bhi(q0) + w1*bhi(q1) + w2*bhi(q2) + w3*bhi(q3);
            }
        }
    }

    bf16* dpix = feat + ((size_t)(by+1)*FCOLS + (bx+1))*CINP;
    uint u0 = f2bu(va[0]) | (f2bu(va[1]) << 16);
    uint u1 = f2bu(va[2]) | (f2bu(va[3]) << 16);
    uint u2 = f2bu(va[4]) | (f2bu(vb[0]) << 16);
    uint u3 = f2bu(vb[1]) | (f2bu(vb[2]) << 16);
    uint u4 = f2bu(vb[3]) | (f2bu(vb[4]) << 16);
    char* dst = (char*)(dpix + c2*5);
    *(uint4a*)dst = (uint4a){u0, u1, u2, u3};
    *(uint*)(dst + 16) = u4;
    if (lane < 15) {
        int j = lane / 5, l = lane - j*5;
        float v = (j == 0) ? xw : (j == 1) ? yw : (-1.f + 0.5f*(float)l);
        dpix[CH*5 + lane] = __float2bfloat16(v);
    }
}

// ---------------------------------------------------------------------------
// Kernel C v6: implicit-GEMM conv, K-split x4, TLP-first structure.
// Grid (15,15,4) = 900 blocks, 256 thr, __launch_bounds__(256,3) -> 3 blk/CU.
// Block = 128oc x (8r x 16c) px; wave = 64oc x 64px (oh = oc-half,
// ph = row-half): m=4, f=4, acc 64 VGPR (square tile = min operand traffic).
// Weights: NOT in LDS -- register double-buffer from wbf2 (L2-resident,
// fragment-packed, 4 coalesced 1KB loads/phase; 32 VGPR total, no R6 spill).
// LDS: B-halo only, 2 x 12KB dbuf (10x18 px + pad), proven swizzle scheme.
// Barriers: 1 per cin-tile (7/block vs 54); within a tile waves free-run,
// compiler waitcnts + 12 waves/CU hide L2/LDS latency (m114 TLP mechanism).
// Per wave-phase: 4 ds_read_b128 + 4 global 1KB + 16 MFMA -> matrix-bound.
// ---------------------------------------------------------------------------
__global__ __launch_bounds__(256, 3) void conv_mfma_kernel(
    const bf16* __restrict__ feat,     // [124][242][672]
    const bf16* __restrict__ wbf2,     // packed A fragments
    bf16* __restrict__ part)           // [4][128][28800]
{
    __shared__ __align__(16) char lds[24576];   // 2 x 12KB halo
    const int tid  = threadIdx.x;
    const int wv   = tid >> 6;
    const int lane = tid & 63;
    const int t15  = tid & 15;
    const int kgl  = (tid >> 4) & 3;
    const int oh   = wv >> 1;              // oc half 0..1
    const int ph   = wv & 1;               // px row-half 0..1
    const int y0p = blockIdx.y * 8;        // 15 row-tiles (also output base)
    const int x0p = blockIdx.x * 16;       // 15 col-tiles (exact, no clamp)
    const int q   = blockIdx.z;
    const int ct0 = q ? (1 + 5*q) : 0;     // 0,6,11,16
    const int nct = q ? 5 : 6;

    f32x4 acc[4][4];
    #pragma unroll
    for (int m = 0; m < 4; ++m)
        #pragma unroll
        for (int f = 0; f < 4; ++f)
            acc[m][f] = (f32x4){0.f, 0.f, 0.f, 0.f};

    // 12-chunk halo (3 loads/wave). 192 px slots; 180 real (10 rows x 18),
    // slots 180..191 pad at row 10 (y0p+10 <= 122 < FROWS, never consumed).
    auto stageH = [&](int ct, int hb) {
        #pragma unroll
        for (int k = 0; k < 3; ++k) {
            int j = wv*3 + k;                        // 0..11
            int cch = j*64 + lane;
            int pp = cch >> 2, kgp = cch & 3;
            int kg = kgp ^ ((pp >> 1) & 3);          // source-side swizzle
            int row = pp / 18;
            int col = pp - row*18;
            const bf16* src = feat + ((size_t)(y0p + row)*FCOLS + (x0p + col))*CINP
                                   + ct*32 + kg*8;
            __builtin_amdgcn_global_load_lds((const G_AS void*)src,
                                             (L_AS void*)(lds + hb + j*1024),
                                             16, 0, 0);
        }
    };
    // A fragments: 4 coalesced 1KB loads from packed wbf2 (L2-resident)
    auto loadA = [&](int ct, int off, s16x8* A) {
        const s16x8* pa = (const s16x8*)wbf2
                        + (size_t)((off*NCT + ct)*8 + oh*4)*64 + lane;
        #pragma unroll
        for (int m = 0; m < 4; ++m) A[m] = pa[m*64];
    };

    s16x8 A0[4], A1[4];
    stageH(ct0, 0);
    loadA(ct0, 0, A0);
    __syncthreads();                       // drains prologue staging

    for (int c = 0; c < nct; ++c) {
        const int ct = ct0 + c;
        const int hb = (c & 1) ? 12288 : 0;
        if (c + 1 < nct) stageH(ct + 1, hb ^ 12288);
        #pragma unroll
        for (int off = 0; off < 9; ++off) {
            s16x8* Ac = (off & 1) ? A1 : A0;         // static (unrolled)
            s16x8* An = (off & 1) ? A0 : A1;
            if (off < 8)            loadA(ct, off + 1, An);
            else if (c + 1 < nct)   loadA(ct + 1, 0, An);
            const int ky = off / 3, kx = off - ky*3;
            s16x8 B[4];
            #pragma unroll
            for (int f = 0; f < 4; ++f) {
                int hp = (ph*4 + f + ky)*18 + t15 + kx;
                B[f] = *(const s16x8*)(lds + hb + hp*64
                                       + ((kgl ^ ((hp >> 1) & 3)) << 4));
            }
            __builtin_amdgcn_s_setprio(1);
            #pragma unroll
            for (int f = 0; f < 4; ++f)
                #pragma unroll
                for (int m = 0; m < 4; ++m)
                    acc[m][f] = __builtin_amdgcn_mfma_f32_16x16x32_bf16(
                                    Ac[m], B[f], acc[m][f], 0, 0, 0);
            __builtin_amdgcn_s_setprio(0);
        }
        if (c + 1 < nct) {       // off=8 used A0, preloaded next into A1
            #pragma unroll
            for (int m = 0; m < 4; ++m) A0[m] = A1[m];
        }
        __syncthreads();         // halo dbuf handoff (drains H prefetch)
    }

    bf16* pq = part + (size_t)q * (128*NPIX);
    const int x = x0p + t15;
    #pragma unroll
    for (int f = 0; f < 4; ++f) {
        const int y = y0p + ph*4 + f;
        #pragma unroll
        for (int m = 0; m < 4; ++m) {
            #pragma unroll
            for (int r = 0; r < 4; ++r) {
                int oc = oh*64 + m*16 + kgl*4 + r;   // D: row=(lane>>4)*4+r
                pq[(size_t)oc*NPIX + y*BW + x] = __float2bfloat16(acc[m][f][r]);
            }
        }
    }
}

// ---------------------------------------------------------------------------
// Kernel R: out[oc][pix] = sum_q part[q][oc][pix] + bias[oc]
// ---------------------------------------------------------------------------
__global__ __launch_bounds__(256) void combine_kernel(
    const bf16* __restrict__ part, const float* __restrict__ bias,
    float* __restrict__ out)
{
    int i8 = blockIdx.x * 256 + threadIdx.x;
    if (i8 >= 128*NPIX/8) return;
    int oc = i8 / (NPIX/8);
    float s[8];
    float b = bias[oc];
    #pragma unroll
    for (int k = 0; k < 8; ++k) s[k] = b;
    #pragma unroll
    for (int qq = 0; qq < 4; ++qq) {
        s16x8 v = *(const s16x8*)(part + (size_t)qq*(128*NPIX) + (size_t)i8*8);
        #pragma unroll
        for (int k = 0; k < 8; ++k) s[k] += bf2f((unsigned short)v[k]);
    }
    f32x4* o = (f32x4*)(out + (size_t)i8*8);
    o[0] = (f32x4){s[0], s[1], s[2], s[3]};
    o[1] = (f32x4){s[4], s[5], s[6], s[7]};
}

// ---------------------------------------------------------------------------
extern "C" void kernel_launch(void* const* d_in, const int* in_sizes, int n_in,
                              void* d_out, int out_size, void* d_ws, size_t ws_size,
                              hipStream_t stream)
{
    const float* cam_feat = (const float*)d_in[0];
    const float* ego2cam  = (const float*)d_in[1];
    const float* conv_w   = (const float*)d_in[2];
    const float* conv_b   = (const float*)d_in[3];
    const int*   img_h    = (const int*)d_in[4];
    const int*   img_w    = (const int*)d_in[5];
    float* out = (float*)d_out;

    // ws (all bf16): camt 17.3MB | feat 40.3MB | wbf2 1.5MB | part 29.5MB
    bf16* camt = (bf16*)d_ws;
    bf16* feat = camt + (size_t)NCAM*CH*FH*FW;
    bf16* wbf2 = feat + (size_t)FROWS*FCOLS*CINP;
    bf16* part = wbf2 + (size_t)9*NCT*8*64*8;

    transpose_kernel<<<dim3(6, FH, NCAM), 256, 0, stream>>>(cam_feat, camt);
    wprep2_kernel<<<168, 256, 0, stream>>>(conv_w, wbf2);
    border_kernel<<<724, 128, 0, stream>>>(feat);
    proj_kernel<<<NPIX/4, 256, 0, stream>>>(camt, ego2cam, img_h, img_w, feat);
    conv_mfma_kernel<<<dim3(15, 15, 4), 256, 0, stream>>>(feat, wbf2, part);
    combine_kernel<<<(128*NPIX/8 + 255)/256, 256, 0, stream>>>(part, conv_b, out);
}

// Round 12
// 105.154 us; speedup vs baseline: 1.1572x; 1.1572x over previous
//
#include <hip/hip_runtime.h>
#include <hip/hip_bf16.h>

#define BH 120
#define BW 240
#define NLVL 5
#define NCAM 6
#define CH 128
#define FH 64
#define FW 176
#define CIN 655
#define CINP 672            // padded to 21*32
#define NCT 21
#define FROWS 124           // padded rows; 0..121 used, 122..123 slack
#define FCOLS 242
#define NPIX (BH*BW)

typedef __hip_bfloat16 bf16;
typedef __attribute__((ext_vector_type(8))) short s16x8;
typedef __attribute__((ext_vector_type(4))) float f32x4;
typedef unsigned int uint;
typedef __attribute__((ext_vector_type(4), aligned(4))) uint uint4a;

#define G_AS __attribute__((address_space(1)))
#define L_AS __attribute__((address_space(3)))

__device__ __forceinline__ float bf2f(unsigned short u) {
    union { unsigned int i; float f; } c; c.i = ((unsigned int)u) << 16; return c.f;
}
__device__ __forceinline__ uint f2bu(float x) {
    return (uint)__hip_bfloat16_raw(__float2bfloat16(x)).x;
}
__device__ __forceinline__ float blo(uint u) {
    union { uint i; float f; } c; c.i = u << 16; return c.f;
}
__device__ __forceinline__ float bhi(uint u) {
    union { uint i; float f; } c; c.i = u & 0xFFFF0000u; return c.f;
}

// ---------------------------------------------------------------------------
// Kernel T: transpose cam_feat [6][128][64][176] f32 -> camt bf16 [6][64][176][128]
// ---------------------------------------------------------------------------
__global__ __launch_bounds__(256) void transpose_kernel(
    const float* __restrict__ in, bf16* __restrict__ out)
{
    __shared__ float t[32][129];
    int n = blockIdx.z, h = blockIdx.y, w0 = blockIdx.x * 32;
    int wlim = min(32, FW - w0);
    int wx = threadIdx.x & 31, cg = threadIdx.x >> 5;
    if (wx < wlim) {
        #pragma unroll
        for (int k = 0; k < 16; ++k) {
            int c = cg + k * 8;
            t[wx][c] = in[((n*CH + c)*FH + h)*FW + w0 + wx];
        }
    }
    __syncthreads();
    int c2 = threadIdx.x & 127, wi = threadIdx.x >> 7;
    for (int w = wi; w < wlim; w += 2)
        out[((n*FH + h)*FW + w0 + w)*CH + c2] = __float2bfloat16(t[w][c2]);
}

// ---------------------------------------------------------------------------
// Kernel W: conv_w [128][655][3][3] f32 -> wbf [9][128][672] bf16 (tail zero)
// ---------------------------------------------------------------------------
__global__ __launch_bounds__(256) void wprep_kernel(
    const float* __restrict__ w, bf16* __restrict__ wbf)
{
    int idx = blockIdx.x * 256 + threadIdx.x;
    if (idx >= 128 * CINP) return;
    int oc = idx / CINP, cin = idx - oc * CINP;
    float v[9];
    if (cin < CIN) {
        const float* s = w + ((size_t)oc * CIN + cin) * 9;
        #pragma unroll
        for (int k = 0; k < 9; ++k) v[k] = s[k];
    } else {
        #pragma unroll
        for (int k = 0; k < 9; ++k) v[k] = 0.f;
    }
    #pragma unroll
    for (int k = 0; k < 9; ++k)
        wbf[(size_t)(k * 128 + oc) * CINP + cin] = __float2bfloat16(v[k]);
}

// ---------------------------------------------------------------------------
// Kernel Z: zero the 724 border pixels across all 672 cin.
// ---------------------------------------------------------------------------
__global__ __launch_bounds__(128) void border_kernel(bf16* __restrict__ feat)
{
    int b = blockIdx.x;            // 0..723
    int row, col;
    if (b < 242)      { row = 0;   col = b; }
    else if (b < 484) { row = 121; col = b - 242; }
    else if (b < 604) { row = b - 484 + 1; col = 0; }
    else              { row = b - 604 + 1; col = 241; }
    s16x8* p = (s16x8*)(feat + ((size_t)row*FCOLS + col)*CINP);
    int t = threadIdx.x;
    if (t < 84) p[t] = (s16x8){0,0,0,0,0,0,0,0};
}

// ---------------------------------------------------------------------------
// Kernel P v3: 1 wave = 1 BEV pixel; camt bf16; XCD-swizzled blockIdx.
// (unchanged from rounds 7-10 passing versions)
// ---------------------------------------------------------------------------
__global__ __launch_bounds__(256) void proj_kernel(
    const bf16* __restrict__ camt,
    const float* __restrict__ e2c,
    const int* __restrict__ pimgh, const int* __restrict__ pimgw,
    bf16* __restrict__ feat)
{
    __shared__ int   s_soff[4][32];
    __shared__ float s_w4[4][30][4];
    __shared__ int   s_val[4][32];

    const int wv = threadIdx.x >> 6;
    const int lane = threadIdx.x & 63;
    const int bid = blockIdx.x;                      // 7200 blocks
    const int swz = (bid & 7) * 900 + (bid >> 3);    // T1 XCD swizzle
    const int pix = swz * 4 + wv;
    const int bx = pix % BW, by = pix / BW;
    float xw = (float)(-30.0 + bx * (60.0/239.0)); if (bx == BW-1) xw = 30.f;
    float yw = (float)(-15.0 + by * (30.0/119.0)); if (by == BH-1) yw = 15.f;

    const bool act = lane < 30;
    int valid = 0, ix = 0, iy = 0, cam = 0;
    float fx = 0.f, fy = 0.f;
    if (act) {
        int l = lane / 6; cam = lane - l*6;
        float h = -1.f + 0.5f * (float)l;
        const float* M = e2c + cam * 16;
        float cx = M[0]*xw + M[1]*yw + M[2]*h  + M[3];
        float cy = M[4]*xw + M[5]*yw + M[6]*h  + M[7];
        float cz = M[8]*xw + M[9]*yw + M[10]*h + M[11];
        float iw = (float)pimgw[0], ih = (float)pimgh[0];
        float px = ((cx/cz + 1e-9f)/iw - 0.5f) * 2.f;
        float py = ((cy/cz + 1e-9f)/ih - 0.5f) * 2.f;
        valid = (cz > 1e-9f) && (px > -1.f) && (px < 1.f)
                             && (py > -1.f) && (py < 1.f);
        float xs = ((px + 1.f)*(float)FW - 1.f) * 0.5f;
        float ys = ((py + 1.f)*(float)FH - 1.f) * 0.5f;
        float x0 = floorf(xs), y0 = floorf(ys);
        fx = xs - x0; fy = ys - y0;
        ix = (int)x0; iy = (int)y0;
        s_val[wv][lane] = valid;
    }
    __syncthreads();
    if (act) {
        int lbase = (lane / 6) * 6;
        int cnt = s_val[wv][lbase] + s_val[wv][lbase+1] + s_val[wv][lbase+2]
                + s_val[wv][lbase+3] + s_val[wv][lbase+4] + s_val[wv][lbase+5];
        float inv = (cnt > 0) ? (1.f / (float)cnt) : 0.f;
        float sc = valid ? inv : 0.f;
        int bx0 = min(max(ix, 0), FW-2);
        int by0 = min(max(iy, 0), FH-2);
        float gx0 = (1.f - fx) * sc, gx1 = fx * sc;
        float wx0 = 0.f, wx1 = 0.f;
        if (ix >= 0)     { if (ix == bx0) wx0 += gx0; else wx1 += gx0; }
        if (ix+1 <= FW-1){ if (ix+1 == bx0) wx0 += gx1; else wx1 += gx1; }
        float wy0 = 0.f, wy1 = 0.f;
        float gy0 = 1.f - fy, gy1 = fy;
        if (iy >= 0)     { if (iy == by0) wy0 += gy0; else wy1 += gy0; }
        if (iy+1 <= FH-1){ if (iy+1 == by0) wy0 += gy1; else wy1 += gy1; }
        s_w4[wv][lane][0] = wx0 * wy0;
        s_w4[wv][lane][1] = wx0 * wy1;
        s_w4[wv][lane][2] = wx1 * wy0;
        s_w4[wv][lane][3] = wx1 * wy1;
        s_soff[wv][lane] = valid ? ((cam*FH + by0)*FW + bx0)*CH : -1;
    }
    __syncthreads();

    const int c2 = lane * 2;
    float va[NLVL], vb[NLVL];
    #pragma unroll
    for (int l = 0; l < NLVL; ++l) { va[l] = 0.f; vb[l] = 0.f; }

    #pragma unroll
    for (int l = 0; l < NLVL; ++l) {
        #pragma unroll
        for (int cm = 0; cm < NCAM; ++cm) {
            int id = l*6 + cm;
            int so = s_soff[wv][id];
            if (so >= 0) {                       // wave-uniform branch
                const bf16* bp = camt + so + c2;
                uint q0 = *(const uint*)(bp);
                uint q2 = *(const uint*)(bp + CH);
                uint q1 = *(const uint*)(bp + FW*CH);
                uint q3 = *(const uint*)(bp + FW*CH + CH);
                float w0 = s_w4[wv][id][0], w1 = s_w4[wv][id][1];
                float w2 = s_w4[wv][id][2], w3 = s_w4[wv][id][3];
                va[l] += w0*blo(q0) + w1*blo(q1) + w2*blo(q2) + w3*blo(q3);
                vb[l] += w0*bhi(q0) + w1*bhi(q1) + w2*bhi(q2) + w3*bhi(q3);
            }
        }
    }

    bf16* dpix = feat + ((size_t)(by+1)*FCOLS + (bx+1))*CINP;
    uint u0 = f2bu(va[0]) | (f2bu(va[1]) << 16);
    uint u1 = f2bu(va[2]) | (f2bu(va[3]) << 16);
    uint u2 = f2bu(va[4]) | (f2bu(vb[0]) << 16);
    uint u3 = f2bu(vb[1]) | (f2bu(vb[2]) << 16);
    uint u4 = f2bu(vb[3]) | (f2bu(vb[4]) << 16);
    char* dst = (char*)(dpix + c2*5);
    *(uint4a*)dst = (uint4a){u0, u1, u2, u3};
    *(uint*)(dst + 16) = u4;
    if (lane < 15) {
        int j = lane / 5, l = lane - j*5;
        float v = (j == 0) ? xw : (j == 1) ? yw : (-1.f + 0.5f*(float)l);
        dpix[CH*5 + lane] = __float2bfloat16(v);
    }
}

// ---------------------------------------------------------------------------
// Kernel C (round-5 exact, stageH fixed): implicit-GEMM 3x3 conv via MFMA
// 16x16x32 bf16, K-split x4. Grid (15,15,4): block = 128 oc x (8r x 16c) px,
// 4 waves, wave = 128oc x 32px (m=8, f=2). W+H double-buffered in 40KB LDS
// via global_load_lds, per-phase __syncthreads. Proven 54.3us (round-5
// bench). R11's fail was a bad revert: 22-chunk stageH with 18-wide
// indexing overflowed the 12KB halo buffer. This is the 12-chunk original.
// ---------------------------------------------------------------------------
__global__ __launch_bounds__(256, 4) void conv_mfma_kernel(
    const bf16* __restrict__ feat,     // [124][242][672]
    const bf16* __restrict__ wbf,      // [9][128][672]
    bf16* __restrict__ part)           // [4][128][28800]
{
    __shared__ __align__(16) char lds[40960];
    const int tid  = threadIdx.x;
    const int wv   = tid >> 6;
    const int lane = tid & 63;
    const int t15  = tid & 15;
    const int kgl  = (tid >> 4) & 3;
    const int y0p = blockIdx.y * 8;
    const int x0p = blockIdx.x * 16;
    const int q   = blockIdx.z;
    const int ct0 = q ? (1 + 5*q) : 0;         // 0,6,11,16
    const int nph = (q ? 5 : 6) * 9;

    const int HB0 = 0, HB1 = 12288, WB0 = 24576, WB1 = 32768;

    f32x4 acc[8][2];
    #pragma unroll
    for (int m = 0; m < 8; ++m)
        #pragma unroll
        for (int f = 0; f < 2; ++f)
            acc[m][f] = (f32x4){0.f, 0.f, 0.f, 0.f};

    auto stageW = [&](int ct, int off, int wb) {
        #pragma unroll
        for (int jj = 0; jj < 2; ++jj) {
            int j = 2*wv + jj;                    // 8 wave-issues total
            int cch = j*64 + lane;
            int oc = cch >> 2, kgp = cch & 3;
            int kg = kgp ^ ((oc >> 1) & 3);       // source-side swizzle
            const bf16* src = wbf + ((size_t)(off*128 + oc)*CINP + ct*32 + kg*8);
            __builtin_amdgcn_global_load_lds((const G_AS void*)src,
                                             (L_AS void*)(lds + wb + j*1024),
                                             16, 0, 0);
        }
    };
    // 12-chunk halo (3 loads/wave): pp 0..191, 10 rows x 18 cols + row-10 pad
    // (y0p+10 <= 122 < FROWS, in-bounds, never consumed by MFMA).
    auto stageH = [&](int ct, int hb) {
        #pragma unroll
        for (int kk = 0; kk < 3; ++kk) {
            int j = wv + 4*kk;                    // 12 wave-issues total
            int cch = j*64 + lane;
            int pp = cch >> 2, kgp = cch & 3;     // pp: halo pixel 0..191
            int kg = kgp ^ ((pp >> 1) & 3);
            int row = pp / 18;
            int col = pp - row*18;
            const bf16* src = feat + ((size_t)(y0p + row)*FCOLS + (x0p + col))*CINP
                                   + ct*32 + kg*8;
            __builtin_amdgcn_global_load_lds((const G_AS void*)src,
                                             (L_AS void*)(lds + hb + j*1024),
                                             16, 0, 0);
        }
    };

    stageH(ct0, HB0);
    stageW(ct0, 0, WB0);
    __syncthreads();

    int lct = 0, off = 0;
    for (int p = 0; p < nph; ++p) {
        if (p + 1 < nph) {
            int off1 = off + 1, lct1 = lct;
            if (off1 == 9) { off1 = 0; ++lct1; }
            stageW(ct0 + lct1, off1, ((p+1) & 1) ? WB1 : WB0);
            if (off1 == 0) stageH(ct0 + lct1, (lct1 & 1) ? HB1 : HB0);
        }
        const int wb = (p & 1) ? WB1 : WB0;
        const int hb = (lct & 1) ? HB1 : HB0;
        const int ky = off / 3, kx = off - ky*3;

        s16x8 A[8];
        #pragma unroll
        for (int m = 0; m < 8; ++m) {
            int oc = m*16 + t15;
            A[m] = *(const s16x8*)(lds + wb + oc*64 + ((kgl ^ ((oc>>1)&3)) << 4));
        }
        #pragma unroll
        for (int f = 0; f < 2; ++f) {
            int prow = (2*wv + f + ky)*18 + t15 + kx;
            s16x8 Bv = *(const s16x8*)(lds + hb + prow*64 + ((kgl ^ ((prow>>1)&3)) << 4));
            __builtin_amdgcn_s_setprio(1);
            #pragma unroll
            for (int m = 0; m < 8; ++m)
                acc[m][f] = __builtin_amdgcn_mfma_f32_16x16x32_bf16(A[m], Bv, acc[m][f], 0, 0, 0);
            __builtin_amdgcn_s_setprio(0);
        }
        __syncthreads();
        if (++off == 9) { off = 0; ++lct; }
    }

    bf16* pq = part + (size_t)q * (128*NPIX);
    const int xo = x0p + t15;
    #pragma unroll
    for (int m = 0; m < 8; ++m) {
        #pragma unroll
        for (int r = 0; r < 4; ++r) {
            int oc = m*16 + kgl*4 + r;             // D: row=(lane>>4)*4+r
            #pragma unroll
            for (int f = 0; f < 2; ++f) {
                int y = y0p + 2*wv + f;
                pq[(size_t)oc*NPIX + y*BW + xo] = __float2bfloat16(acc[m][f][r]);
            }
        }
    }
}

// ---------------------------------------------------------------------------
// Kernel R: out[oc][pix] = sum_q part[q][oc][pix] + bias[oc]
// ---------------------------------------------------------------------------
__global__ __launch_bounds__(256) void combine_kernel(
    const bf16* __restrict__ part, const float* __restrict__ bias,
    float* __restrict__ out)
{
    int i8 = blockIdx.x * 256 + threadIdx.x;
    if (i8 >= 128*NPIX/8) return;
    int oc = i8 / (NPIX/8);
    float s[8];
    float b = bias[oc];
    #pragma unroll
    for (int k = 0; k < 8; ++k) s[k] = b;
    #pragma unroll
    for (int qq = 0; qq < 4; ++qq) {
        s16x8 v = *(const s16x8*)(part + (size_t)qq*(128*NPIX) + (size_t)i8*8);
        #pragma unroll
        for (int k = 0; k < 8; ++k) s[k] += bf2f((unsigned short)v[k]);
    }
    f32x4* o = (f32x4*)(out + (size_t)i8*8);
    o[0] = (f32x4){s[0], s[1], s[2], s[3]};
    o[1] = (f32x4){s[4], s[5], s[6], s[7]};
}

// ---------------------------------------------------------------------------
extern "C" void kernel_launch(void* const* d_in, const int* in_sizes, int n_in,
                              void* d_out, int out_size, void* d_ws, size_t ws_size,
                              hipStream_t stream)
{
    const float* cam_feat = (const float*)d_in[0];
    const float* ego2cam  = (const float*)d_in[1];
    const float* conv_w   = (const float*)d_in[2];
    const float* conv_b   = (const float*)d_in[3];
    const int*   img_h    = (const int*)d_in[4];
    const int*   img_w    = (const int*)d_in[5];
    float* out = (float*)d_out;

    // ws (all bf16): camt 17.3MB | feat 40.3MB | wbf 1.5MB | part 29.5MB
    bf16* camt = (bf16*)d_ws;
    bf16* feat = camt + (size_t)NCAM*CH*FH*FW;
    bf16* wbf  = feat + (size_t)FROWS*FCOLS*CINP;
    bf16* part = wbf  + (size_t)9*128*CINP;

    transpose_kernel<<<dim3(6, FH, NCAM), 256, 0, stream>>>(cam_feat, camt);
    wprep_kernel<<<(128*CINP + 255)/256, 256, 0, stream>>>(conv_w, wbf);
    border_kernel<<<724, 128, 0, stream>>>(feat);
    proj_kernel<<<NPIX/4, 256, 0, stream>>>(camt, ego2cam, img_h, img_w, feat);
    conv_mfma_kernel<<<dim3(15, 15, 4), 256, 0, stream>>>(feat, wbf, part);
    combine_kernel<<<(128*NPIX/8 + 255)/256, 256, 0, stream>>>(part, conv_b, out);
}